// Round 1
// baseline (218.632 us; speedup 1.0000x reference)
//
#include <hip/hip_runtime.h>
#include <math.h>

namespace {
constexpr int B2v = 512;
constexpr int NR  = 49;     // regions per view
constexpr int Dv  = 256;    // feature dim
constexpr int KQ  = 128;    // queue K
constexpr float INV_TAU     = 25.0f;  // 1/0.04
constexpr float INV_TAU_STU = 10.0f;  // 1/0.1
constexpr int TSTRIDE = 257;          // padded LDS stride (bank-conflict: 4-way max)
}

__device__ __forceinline__ float wave_max(float v) {
  for (int o = 32; o; o >>= 1) v = fmaxf(v, __shfl_xor(v, o));
  return v;
}
__device__ __forceinline__ float wave_sum(float v) {
  for (int o = 32; o; o >>= 1) v += __shfl_xor(v, o);
  return v;
}

// ---------------------------------------------------------------------------
// k0: normalize use_queue into int mask, robust to bool(1B) vs int32 layout.
// If layout is int32 (values 0/1), every byte at index %4!=0 within the first
// 512 bytes is zero; random bools make that all-zero event probability ~2^-384.
// Reading 512 bytes is in-bounds under both interpretations.
// ---------------------------------------------------------------------------
__global__ __launch_bounds__(512) void k0_mask(const unsigned char* __restrict__ uq,
                                               int* __restrict__ uq_norm) {
  __shared__ int isbool;
  const int t = threadIdx.x;  // 512
  if (t == 0) isbool = 0;
  __syncthreads();
  if ((t & 3) && uq[t]) isbool = 1;  // benign same-value race
  __syncthreads();
  int v = isbool ? (int)uq[t] : ((const int*)uq)[t];
  uq_norm[t] = (v != 0) ? 1 : 0;
}

// ---------------------------------------------------------------------------
// k1: dequeue -> write out_tc, out_tr; per-row softmax stats (max, sumexp)
// for t_reg rows ((tr - center_grid)/TAU) and s_reg rows (s_region/TAU_STU).
// One block per batch b; 4 waves; wave-per-row; float4 loads; shuffle reduce.
// ---------------------------------------------------------------------------
__global__ __launch_bounds__(256) void k1_dequeue(
    const float* __restrict__ s_region_out,
    const float* __restrict__ t_cls_out,
    const float* __restrict__ t_region_out,
    const float* __restrict__ queue_all,
    const float* __restrict__ queue_grid_all,
    const float* __restrict__ center_grid,
    const int* __restrict__ concept_idx,
    const int* __restrict__ pos_idx,
    const int* __restrict__ uq_norm,
    float* __restrict__ out_tc,
    float* __restrict__ out_tr,
    float* __restrict__ tr_stats,   // [B2*NR*2]
    float* __restrict__ sr_stats) { // [B2*NR*2]
  const int b = blockIdx.x;
  const int tid = threadIdx.x;
  const int lane = tid & 63, wave = tid >> 6;
  const bool use = uq_norm[b] != 0;
  const size_t qoff = (size_t)concept_idx[b] * KQ + (size_t)pos_idx[b];
  const float* qg = queue_grid_all + qoff * (size_t)(2 * NR) * Dv;

  // tc (one element per thread)
  {
    float v = use ? queue_all[qoff * Dv + tid] : t_cls_out[(size_t)b * Dv + tid];
    out_tc[(size_t)b * Dv + tid] = v;
  }

  const float4 cg4 = *reinterpret_cast<const float4*>(center_grid + lane * 4);

  // tr rows: write + stats
  for (int r = wave; r < NR; r += 4) {
    const float* src = use ? (qg + (size_t)r * Dv)
                           : (t_region_out + ((size_t)b * NR + r) * Dv);
    float4 v = *reinterpret_cast<const float4*>(src + lane * 4);
    float* o = out_tr + ((size_t)b * NR + r) * Dv + lane * 4;  // 4B-aligned only
    o[0] = v.x; o[1] = v.y; o[2] = v.z; o[3] = v.w;
    float x0 = (v.x - cg4.x) * INV_TAU, x1 = (v.y - cg4.y) * INV_TAU;
    float x2 = (v.z - cg4.z) * INV_TAU, x3 = (v.w - cg4.w) * INV_TAU;
    float m = wave_max(fmaxf(fmaxf(x0, x1), fmaxf(x2, x3)));
    float e = wave_sum(expf(x0 - m) + expf(x1 - m) + expf(x2 - m) + expf(x3 - m));
    if (lane == 0) {
      tr_stats[((size_t)b * NR + r) * 2]     = m;
      tr_stats[((size_t)b * NR + r) * 2 + 1] = e;
    }
  }

  // s_reg rows: stats only
  for (int r = wave; r < NR; r += 4) {
    float4 v = *reinterpret_cast<const float4*>(
        s_region_out + ((size_t)b * NR + r) * Dv + lane * 4);
    float x0 = v.x * INV_TAU_STU, x1 = v.y * INV_TAU_STU;
    float x2 = v.z * INV_TAU_STU, x3 = v.w * INV_TAU_STU;
    float m = wave_max(fmaxf(fmaxf(x0, x1), fmaxf(x2, x3)));
    float e = wave_sum(expf(x0 - m) + expf(x1 - m) + expf(x2 - m) + expf(x3 - m));
    if (lane == 0) {
      sr_stats[((size_t)b * NR + r) * 2]     = m;
      sr_stats[((size_t)b * NR + r) * 2 + 1] = e;
    }
  }
}

// ---------------------------------------------------------------------------
// k2: cls KL term per teacher batch b, student bs = b ^ 256.
// cls_part[b] = 0.5 * sum_d(-softmax((tc-c)/TAU)[d] * log_softmax(s_cls/TAU)[d])
// ---------------------------------------------------------------------------
__global__ __launch_bounds__(64) void k2_cls(
    const float* __restrict__ s_cls_out,
    const float* __restrict__ out_tc,
    const float* __restrict__ center,
    float* __restrict__ cls_part) {
  const int b = blockIdx.x;
  const int bs = b ^ 256;
  const int lane = threadIdx.x;

  const float* tc = out_tc + (size_t)b * Dv + lane * 4;  // 4B aligned
  float t0 = tc[0], t1 = tc[1], t2 = tc[2], t3 = tc[3];
  float4 c4 = *reinterpret_cast<const float4*>(center + lane * 4);
  float x0 = (t0 - c4.x) * INV_TAU, x1 = (t1 - c4.y) * INV_TAU;
  float x2 = (t2 - c4.z) * INV_TAU, x3 = (t3 - c4.w) * INV_TAU;
  float M = wave_max(fmaxf(fmaxf(x0, x1), fmaxf(x2, x3)));
  float e0 = expf(x0 - M), e1 = expf(x1 - M), e2 = expf(x2 - M), e3 = expf(x3 - M);
  float S = wave_sum(e0 + e1 + e2 + e3);
  float rS = 1.0f / S;

  float4 s4 = *reinterpret_cast<const float4*>(s_cls_out + (size_t)bs * Dv + lane * 4);
  float y0 = s4.x * INV_TAU, y1 = s4.y * INV_TAU, y2 = s4.z * INV_TAU, y3 = s4.w * INV_TAU;
  float M2 = wave_max(fmaxf(fmaxf(y0, y1), fmaxf(y2, y3)));
  float S2 = wave_sum(expf(y0 - M2) + expf(y1 - M2) + expf(y2 - M2) + expf(y3 - M2));
  float lse = M2 + logf(S2);

  float part = e0 * rS * (lse - y0) + e1 * rS * (lse - y1) +
               e2 * rS * (lse - y2) + e3 * rS * (lse - y3);
  part = wave_sum(part);
  if (lane == 0) cls_part[b] = 0.5f * part;
}

// ---------------------------------------------------------------------------
// k3: grid term. Block per teacher batch bt (student bs = bt ^ 256).
// Stage dequeued t_fea tile in LDS (padded stride), row norms, then per n:
// 49 dot products -> argmax (first-max tie rule, matching jnp.argmax), then
// accumulate -t_reg[bt,m*,:] * log_softmax(s_reg[bs,n,:]) per-thread over d;
// single block reduction at the end (sum order n then d is reordered legally).
// ---------------------------------------------------------------------------
__global__ __launch_bounds__(256) void k3_grid(
    const float* __restrict__ s_region_out,
    const float* __restrict__ s_fea,
    const float* __restrict__ t_fea,
    const float* __restrict__ queue_grid_all,
    const float* __restrict__ center_grid,
    const float* __restrict__ out_tr,
    const float* __restrict__ tr_stats,
    const float* __restrict__ sr_stats,
    const int* __restrict__ concept_idx,
    const int* __restrict__ pos_idx,
    const int* __restrict__ uq_norm,
    float* __restrict__ grid_part) {
  __shared__ float tT[NR * TSTRIDE];
  __shared__ float tS[Dv];
  __shared__ float pairs[256];
  __shared__ float scores[64];
  __shared__ float rinvS[NR];
  __shared__ float red[4];
  __shared__ int mstar_s;

  const int bt = blockIdx.x;
  const int bs = bt ^ 256;
  const int tid = threadIdx.x;
  const int lane = tid & 63, wave = tid >> 6;
  const bool use = uq_norm[bt] != 0;
  const size_t qoff = (size_t)concept_idx[bt] * KQ + (size_t)pos_idx[bt];
  const float* tf_src = use ? (queue_grid_all + (qoff * (2 * NR) + NR) * (size_t)Dv)
                            : (t_fea + (size_t)bt * NR * Dv);

  // stage dequeued teacher features (49 x 256) into padded LDS
  for (int idx = tid; idx < NR * Dv; idx += 256) {
    int r = idx >> 8, d = idx & 255;
    tT[r * TSTRIDE + d] = tf_src[(size_t)r * Dv + d];
  }
  __syncthreads();

  // per-row inverse norms (wave-per-row)
  for (int r = wave; r < NR; r += 4) {
    float ss = 0.f;
#pragma unroll
    for (int j = 0; j < 4; j++) {
      float v = tT[r * TSTRIDE + lane * 4 + j];
      ss += v * v;
    }
    ss = wave_sum(ss);
    if (lane == 0) rinvS[r] = 1.0f / fmaxf(sqrtf(ss), 1e-12f);
  }
  const float cg = center_grid[tid];
  float acc = 0.f;
  __syncthreads();

  for (int n = 0; n < NR; n++) {
    tS[tid] = s_fea[((size_t)bs * NR + n) * Dv + tid];
    __syncthreads();

    // 49 m * 4 quarters: each thread does a 64-long partial dot
    if (tid < 196) {
      int m = tid >> 2, q = tid & 3;
      float p = 0.f;
      const float* tp = &tT[m * TSTRIDE + q * 64];
      const float* sp = &tS[q * 64];
#pragma unroll 8
      for (int i = 0; i < 64; i++) p += sp[i] * tp[i];
      pairs[tid] = p;
    }
    __syncthreads();
    if (tid < NR)
      scores[tid] = (pairs[tid * 4] + pairs[tid * 4 + 1] +
                     pairs[tid * 4 + 2] + pairs[tid * 4 + 3]) * rinvS[tid];
    __syncthreads();

    // argmax over m with first-index tie-break (jnp.argmax semantics)
    if (wave == 0) {
      float v = (lane < NR) ? scores[lane] : -INFINITY;
      int idx = lane;
      for (int o = 32; o; o >>= 1) {
        float ov = __shfl_xor(v, o);
        int oi = __shfl_xor(idx, o);
        if (ov > v || (ov == v && oi < idx)) { v = ov; idx = oi; }
      }
      if (lane == 0) mstar_s = idx;
    }
    __syncthreads();
    const int ms = mstar_s;

    // accumulate -t_reg[bt,ms,d] * (y_d - lse) with y = s_reg/TAU_STU
    float y = s_region_out[((size_t)bs * NR + n) * Dv + tid] * INV_TAU_STU;
    float smax = sr_stats[((size_t)bs * NR + n) * 2];
    float ssum = sr_stats[((size_t)bs * NR + n) * 2 + 1];
    float lse = smax + logf(ssum);
    float v = out_tr[((size_t)bt * NR + ms) * Dv + tid];
    float tmax = tr_stats[((size_t)bt * NR + ms) * 2];
    float tsum = tr_stats[((size_t)bt * NR + ms) * 2 + 1];
    float treg = expf((v - cg) * INV_TAU - tmax) / tsum;
    acc += treg * (lse - y);
  }

  acc = wave_sum(acc);
  if (lane == 0) red[wave] = acc;
  __syncthreads();
  if (tid == 0)
    grid_part[bt] = (0.5f / 49.0f) * (red[0] + red[1] + red[2] + red[3]);
}

// ---------------------------------------------------------------------------
// k4: deterministic final reduction -> d_out[0] = mean over 512 of
// (cls_part + grid_part)
// ---------------------------------------------------------------------------
__global__ __launch_bounds__(256) void k4_final(const float* __restrict__ cls_part,
                                                const float* __restrict__ grid_part,
                                                float* __restrict__ out) {
  __shared__ float red[4];
  const int tid = threadIdx.x, lane = tid & 63, wave = tid >> 6;
  float a = cls_part[tid] + grid_part[tid] + cls_part[tid + 256] + grid_part[tid + 256];
  a = wave_sum(a);
  if (lane == 0) red[wave] = a;
  __syncthreads();
  if (tid == 0) out[0] = (red[0] + red[1] + red[2] + red[3]) * (1.0f / 512.0f);
}

extern "C" void kernel_launch(void* const* d_in, const int* in_sizes, int n_in,
                              void* d_out, int out_size, void* d_ws, size_t ws_size,
                              hipStream_t stream) {
  (void)in_sizes; (void)n_in; (void)out_size; (void)ws_size;
  const float* s_cls_out      = (const float*)d_in[0];
  const float* s_region_out   = (const float*)d_in[1];
  const float* s_fea          = (const float*)d_in[2];
  const float* t_cls_out      = (const float*)d_in[3];
  const float* t_region_out   = (const float*)d_in[4];
  const float* t_fea          = (const float*)d_in[5];
  const float* queue_all      = (const float*)d_in[6];
  const float* queue_grid_all = (const float*)d_in[7];
  const float* center         = (const float*)d_in[8];
  const float* center_grid    = (const float*)d_in[9];
  const int* concept_idx      = (const int*)d_in[10];
  const int* pos_idx          = (const int*)d_in[11];
  const unsigned char* use_q  = (const unsigned char*)d_in[12];

  float* out    = (float*)d_out;
  float* out_tc = out + 1;                 // 512*256
  float* out_tr = out + 1 + B2v * Dv;      // 25088*256

  float* ws        = (float*)d_ws;
  float* tr_stats  = ws;                       // 2*512*49
  float* sr_stats  = tr_stats + 2 * B2v * NR;  // 2*512*49
  float* cls_part  = sr_stats + 2 * B2v * NR;  // 512
  float* grid_part = cls_part + B2v;           // 512
  int*   uq_norm   = (int*)(grid_part + B2v);  // 512

  k0_mask<<<1, 512, 0, stream>>>(use_q, uq_norm);
  k1_dequeue<<<B2v, 256, 0, stream>>>(s_region_out, t_cls_out, t_region_out,
                                      queue_all, queue_grid_all, center_grid,
                                      concept_idx, pos_idx, uq_norm,
                                      out_tc, out_tr, tr_stats, sr_stats);
  k2_cls<<<B2v, 64, 0, stream>>>(s_cls_out, out_tc, center, cls_part);
  k3_grid<<<B2v, 256, 0, stream>>>(s_region_out, s_fea, t_fea, queue_grid_all,
                                   center_grid, out_tr, tr_stats, sr_stats,
                                   concept_idx, pos_idx, uq_norm, grid_part);
  k4_final<<<1, 256, 0, stream>>>(cls_part, grid_part, out);
}

// Round 2
// 97.758 us; speedup vs baseline: 2.2365x; 2.2365x over previous
//
#include <hip/hip_runtime.h>
#include <math.h>

namespace {
constexpr int B2v = 512;
constexpr int NR  = 49;     // regions per view
constexpr int Dv  = 256;    // feature dim
constexpr int KQ  = 128;    // queue K
constexpr float INV_TAU     = 25.0f;  // 1/0.04
constexpr float INV_TAU_STU = 10.0f;  // 1/0.1
constexpr int ROWS    = B2v * NR;     // 25088
constexpr int NB_LOSS = ROWS / 4;     // 6272
constexpr int NB_CLS  = B2v / 4;      // 128
}

__device__ __forceinline__ float wave_max(float v) {
  for (int o = 32; o; o >>= 1) v = fmaxf(v, __shfl_xor(v, o));
  return v;
}
__device__ __forceinline__ float wave_sum(float v) {
  for (int o = 32; o; o >>= 1) v += __shfl_xor(v, o);
  return v;
}
__device__ __forceinline__ int swz(int r) { return (r >> 2) & 7; }

// ---------------------------------------------------------------------------
// k0: normalize use_queue into int mask, robust to bool(1B) vs int32 layout.
// ---------------------------------------------------------------------------
__global__ __launch_bounds__(512) void k0_mask(const unsigned char* __restrict__ uq,
                                               int* __restrict__ uq_norm) {
  __shared__ int isbool;
  const int t = threadIdx.x;  // 512
  if (t == 0) isbool = 0;
  __syncthreads();
  if ((t & 3) && uq[t]) isbool = 1;  // benign same-value race
  __syncthreads();
  int v = isbool ? (int)uq[t] : ((const int*)uq)[t];
  uq_norm[t] = (v != 0) ? 1 : 0;
}

// ---------------------------------------------------------------------------
// k1: pure dequeue copy -> out_tc, out_tr (write-only outputs; misaligned by
// the leading loss scalar so stores are coalesced scalars).
// ---------------------------------------------------------------------------
__global__ __launch_bounds__(256) void k1_dequeue(
    const float* __restrict__ t_cls_out,
    const float* __restrict__ t_region_out,
    const float* __restrict__ queue_all,
    const float* __restrict__ queue_grid_all,
    const int* __restrict__ concept_idx,
    const int* __restrict__ pos_idx,
    const int* __restrict__ uq_norm,
    float* __restrict__ out_tc,
    float* __restrict__ out_tr) {
  const int b = blockIdx.x;
  const int tid = threadIdx.x;
  const int lane = tid & 63, wave = tid >> 6;
  const bool use = uq_norm[b] != 0;
  const size_t qoff = (size_t)concept_idx[b] * KQ + (size_t)pos_idx[b];
  const float* qg = queue_grid_all + qoff * (size_t)(2 * NR) * Dv;

  out_tc[(size_t)b * Dv + tid] =
      use ? queue_all[qoff * Dv + tid] : t_cls_out[(size_t)b * Dv + tid];

  for (int r = wave; r < NR; r += 4) {
    const float* src = use ? (qg + (size_t)r * Dv)
                           : (t_region_out + ((size_t)b * NR + r) * Dv);
    float4 v = *reinterpret_cast<const float4*>(src + lane * 4);
    float* o = out_tr + ((size_t)b * NR + r) * Dv + lane * 4;  // 4B-aligned only
    o[0] = v.x; o[1] = v.y; o[2] = v.z; o[3] = v.w;
  }
}

// ---------------------------------------------------------------------------
// k3a: per-bt 49x49 sim matrix via 4x4 register tiles from swizzled LDS,
// then argmax over m (first-index tie-break) -> ms_idx[bt*49+n].
// LDS layout: word(r, i) = r*256 + (i ^ (swz(r)<<2)); b128-safe, conflict-free
// for the 4-row-group access pattern (row>>2 varies across lanes).
// ---------------------------------------------------------------------------
__global__ __launch_bounds__(256) void k3a_argmax(
    const float* __restrict__ s_fea,
    const float* __restrict__ t_fea,
    const float* __restrict__ queue_grid_all,
    const int* __restrict__ concept_idx,
    const int* __restrict__ pos_idx,
    const int* __restrict__ uq_norm,
    int* __restrict__ ms_idx) {
  __shared__ __align__(16) float tS[52 * 256];
  __shared__ __align__(16) float tT[52 * 256];
  __shared__ float scores[52 * 56];
  __shared__ float rinv[52];

  const int bt = blockIdx.x, bs = bt ^ 256;
  const int tid = threadIdx.x, lane = tid & 63, wave = tid >> 6;
  const bool use = uq_norm[bt] != 0;
  const size_t qoff = (size_t)concept_idx[bt] * KQ + (size_t)pos_idx[bt];
  const float* tf = use ? (queue_grid_all + (qoff * (2 * NR) + NR) * (size_t)Dv)
                        : (t_fea + (size_t)bt * NR * Dv);
  const float* sf = s_fea + (size_t)bs * NR * Dv;

  // stage both 49x256 tiles (swizzled quads)
  for (int idx = tid; idx < NR * 64; idx += 256) {
    int r = idx >> 6, q = idx & 63;
    int dst = r * 256 + 4 * (q ^ swz(r));
    *reinterpret_cast<float4*>(&tS[dst]) =
        *reinterpret_cast<const float4*>(sf + (size_t)r * Dv + 4 * q);
    *reinterpret_cast<float4*>(&tT[dst]) =
        *reinterpret_cast<const float4*>(tf + (size_t)r * Dv + 4 * q);
  }
  __syncthreads();

  // teacher row inverse norms
  for (int r = wave; r < NR; r += 4) {
    float4 v = *reinterpret_cast<const float4*>(&tT[r * 256 + 4 * (lane ^ swz(r))]);
    float ss = v.x * v.x + v.y * v.y + v.z * v.z + v.w * v.w;
    ss = wave_sum(ss);
    if (lane == 0) rinv[r] = 1.0f / fmaxf(sqrtf(ss), 1e-12f);
  }
  __syncthreads();

  // 4x4 register-tiled dot: thread t -> n-rows 4*(t/13).., m-rows 4*(t%13)..
  float c[4][4] = {};
  const int tu = tid / 13, tv = tid - tu * 13;
  if (tid < 169) {
    const float* As = &tS[(tu * 4) * 256];
    const float* Bs = &tT[(tv * 4) * 256];
    const int sA = tu & 7, sB = tv & 7;
#pragma unroll 4
    for (int ib = 0; ib < 64; ib++) {
      float4 a[4], b[4];
      const int ca = 4 * (ib ^ sA), cb = 4 * (ib ^ sB);
#pragma unroll
      for (int j = 0; j < 4; j++)
        a[j] = *reinterpret_cast<const float4*>(As + j * 256 + ca);
#pragma unroll
      for (int k = 0; k < 4; k++)
        b[k] = *reinterpret_cast<const float4*>(Bs + k * 256 + cb);
#pragma unroll
      for (int j = 0; j < 4; j++)
#pragma unroll
        for (int k = 0; k < 4; k++)
          c[j][k] += a[j].x * b[k].x + a[j].y * b[k].y +
                     a[j].z * b[k].z + a[j].w * b[k].w;
    }
#pragma unroll
    for (int j = 0; j < 4; j++)
#pragma unroll
      for (int k = 0; k < 4; k++) {
        int m = tv * 4 + k;
        scores[(tu * 4 + j) * 56 + m] =
            (m < NR) ? c[j][k] * rinv[m] : -INFINITY;
      }
  }
  __syncthreads();

  // argmax over m per n, first-index tie-break (jnp.argmax semantics)
  for (int n = wave; n < NR; n += 4) {
    float v = (lane < NR) ? scores[n * 56 + lane] : -INFINITY;
    int idx = lane;
    for (int o = 32; o; o >>= 1) {
      float ov = __shfl_xor(v, o);
      int oi = __shfl_xor(idx, o);
      if (ov > v || (ov == v && oi < idx)) { v = ov; idx = oi; }
    }
    if (lane == 0) ms_idx[bt * NR + n] = idx;
  }
}

// ---------------------------------------------------------------------------
// k3bc: blocks [0,6272): wave-per-(bt,n) grid-loss row, softmax stats inline,
// gather teacher row from aligned sources. blocks [6272,6400): cls KL term,
// wave-per-bt.
// ---------------------------------------------------------------------------
__global__ __launch_bounds__(256) void k3bc_loss(
    const float* __restrict__ s_cls_out,
    const float* __restrict__ s_region_out,
    const float* __restrict__ t_cls_out,
    const float* __restrict__ t_region_out,
    const float* __restrict__ queue_all,
    const float* __restrict__ queue_grid_all,
    const float* __restrict__ center,
    const float* __restrict__ center_grid,
    const int* __restrict__ concept_idx,
    const int* __restrict__ pos_idx,
    const int* __restrict__ uq_norm,
    const int* __restrict__ ms_idx,
    float* __restrict__ block_part,
    float* __restrict__ cls_part) {
  const int tid = threadIdx.x, lane = tid & 63, wave = tid >> 6;

  if (blockIdx.x < NB_LOSS) {
    __shared__ float red[4];
    const int row = blockIdx.x * 4 + wave;
    const int bt = row / NR, n = row - bt * NR, bs = bt ^ 256;

    // student log-softmax over s_region row (bs, n)
    float4 y4 = *reinterpret_cast<const float4*>(
        s_region_out + ((size_t)bs * NR + n) * Dv + lane * 4);
    float y0 = y4.x * INV_TAU_STU, y1 = y4.y * INV_TAU_STU;
    float y2 = y4.z * INV_TAU_STU, y3 = y4.w * INV_TAU_STU;
    float smax = wave_max(fmaxf(fmaxf(y0, y1), fmaxf(y2, y3)));
    float ssum = wave_sum(expf(y0 - smax) + expf(y1 - smax) +
                          expf(y2 - smax) + expf(y3 - smax));
    float lse = smax + logf(ssum);

    // teacher softmax over dequeued t_region row (bt, ms)
    const int ms = ms_idx[bt * NR + n];
    const bool use = uq_norm[bt] != 0;
    const size_t qoff = (size_t)concept_idx[bt] * KQ + (size_t)pos_idx[bt];
    const float* trow = use
        ? (queue_grid_all + (qoff * (2 * NR) + ms) * (size_t)Dv)
        : (t_region_out + ((size_t)bt * NR + ms) * Dv);
    float4 v4 = *reinterpret_cast<const float4*>(trow + lane * 4);
    float4 cg4 = *reinterpret_cast<const float4*>(center_grid + lane * 4);
    float x0 = (v4.x - cg4.x) * INV_TAU, x1 = (v4.y - cg4.y) * INV_TAU;
    float x2 = (v4.z - cg4.z) * INV_TAU, x3 = (v4.w - cg4.w) * INV_TAU;
    float tmax = wave_max(fmaxf(fmaxf(x0, x1), fmaxf(x2, x3)));
    float e0 = expf(x0 - tmax), e1 = expf(x1 - tmax);
    float e2 = expf(x2 - tmax), e3 = expf(x3 - tmax);
    float tsum = wave_sum(e0 + e1 + e2 + e3);

    float part = wave_sum(e0 * (lse - y0) + e1 * (lse - y1) +
                          e2 * (lse - y2) + e3 * (lse - y3));
    if (lane == 0) red[wave] = part / tsum;
    __syncthreads();
    if (tid == 0)
      block_part[blockIdx.x] = red[0] + red[1] + red[2] + red[3];
  } else {
    const int b = (blockIdx.x - NB_LOSS) * 4 + wave;
    const int bsx = b ^ 256;
    const bool use = uq_norm[b] != 0;
    const size_t qoff = (size_t)concept_idx[b] * KQ + (size_t)pos_idx[b];
    const float* tc = use ? (queue_all + qoff * Dv) : (t_cls_out + (size_t)b * Dv);

    float4 t4 = *reinterpret_cast<const float4*>(tc + lane * 4);
    float4 c4 = *reinterpret_cast<const float4*>(center + lane * 4);
    float x0 = (t4.x - c4.x) * INV_TAU, x1 = (t4.y - c4.y) * INV_TAU;
    float x2 = (t4.z - c4.z) * INV_TAU, x3 = (t4.w - c4.w) * INV_TAU;
    float M = wave_max(fmaxf(fmaxf(x0, x1), fmaxf(x2, x3)));
    float e0 = expf(x0 - M), e1 = expf(x1 - M), e2 = expf(x2 - M), e3 = expf(x3 - M);
    float S = wave_sum(e0 + e1 + e2 + e3);

    float4 s4 = *reinterpret_cast<const float4*>(
        s_cls_out + (size_t)bsx * Dv + lane * 4);
    float z0 = s4.x * INV_TAU, z1 = s4.y * INV_TAU;
    float z2 = s4.z * INV_TAU, z3 = s4.w * INV_TAU;
    float M2 = wave_max(fmaxf(fmaxf(z0, z1), fmaxf(z2, z3)));
    float S2 = wave_sum(expf(z0 - M2) + expf(z1 - M2) +
                        expf(z2 - M2) + expf(z3 - M2));
    float lse = M2 + logf(S2);

    float part = wave_sum(e0 * (lse - z0) + e1 * (lse - z1) +
                          e2 * (lse - z2) + e3 * (lse - z3));
    if (lane == 0) cls_part[b] = 0.5f * part / S;
  }
}

// ---------------------------------------------------------------------------
// k4: deterministic final reduction.
// out[0] = (sum(cls_part) + (0.5/49)*sum(block_part)) / 512
// ---------------------------------------------------------------------------
__global__ __launch_bounds__(256) void k4_final(const float* __restrict__ cls_part,
                                                const float* __restrict__ block_part,
                                                float* __restrict__ out) {
  __shared__ float red[4];
  const int tid = threadIdx.x, lane = tid & 63, wave = tid >> 6;
  float a = 0.f;
  for (int i = tid; i < NB_LOSS; i += 256) a += block_part[i];
  float c = cls_part[tid] + cls_part[tid + 256];
  float local = c + (0.5f / 49.0f) * a;
  local = wave_sum(local);
  if (lane == 0) red[wave] = local;
  __syncthreads();
  if (tid == 0)
    out[0] = (red[0] + red[1] + red[2] + red[3]) * (1.0f / 512.0f);
}

extern "C" void kernel_launch(void* const* d_in, const int* in_sizes, int n_in,
                              void* d_out, int out_size, void* d_ws, size_t ws_size,
                              hipStream_t stream) {
  (void)in_sizes; (void)n_in; (void)out_size; (void)ws_size;
  const float* s_cls_out      = (const float*)d_in[0];
  const float* s_region_out   = (const float*)d_in[1];
  const float* s_fea          = (const float*)d_in[2];
  const float* t_cls_out      = (const float*)d_in[3];
  const float* t_region_out   = (const float*)d_in[4];
  const float* t_fea          = (const float*)d_in[5];
  const float* queue_all      = (const float*)d_in[6];
  const float* queue_grid_all = (const float*)d_in[7];
  const float* center         = (const float*)d_in[8];
  const float* center_grid    = (const float*)d_in[9];
  const int* concept_idx      = (const int*)d_in[10];
  const int* pos_idx          = (const int*)d_in[11];
  const unsigned char* use_q  = (const unsigned char*)d_in[12];

  float* out    = (float*)d_out;
  float* out_tc = out + 1;                 // 512*256
  float* out_tr = out + 1 + B2v * Dv;      // 25088*256

  float* ws         = (float*)d_ws;
  float* cls_part   = ws;                        // 512
  float* block_part = cls_part + B2v;            // 6272
  int*   ms_idx     = (int*)(block_part + NB_LOSS);  // 25088
  int*   uq_norm    = ms_idx + ROWS;             // 512

  k0_mask<<<1, 512, 0, stream>>>(use_q, uq_norm);
  k1_dequeue<<<B2v, 256, 0, stream>>>(t_cls_out, t_region_out, queue_all,
                                      queue_grid_all, concept_idx, pos_idx,
                                      uq_norm, out_tc, out_tr);
  k3a_argmax<<<B2v, 256, 0, stream>>>(s_fea, t_fea, queue_grid_all,
                                      concept_idx, pos_idx, uq_norm, ms_idx);
  k3bc_loss<<<NB_LOSS + NB_CLS, 256, 0, stream>>>(
      s_cls_out, s_region_out, t_cls_out, t_region_out, queue_all,
      queue_grid_all, center, center_grid, concept_idx, pos_idx, uq_norm,
      ms_idx, block_part, cls_part);
  k4_final<<<1, 256, 0, stream>>>(cls_part, block_part, out);
}

// Round 3
// 53.039 us; speedup vs baseline: 4.1221x; 1.8431x over previous
//
#include <hip/hip_runtime.h>
#include <math.h>

namespace {
constexpr int B2v = 512;
constexpr int NR  = 49;     // regions per view
constexpr int NP  = 64;     // padded rows for MFMA tile
constexpr int Dv  = 256;    // feature dim
constexpr int KQ  = 128;    // queue K
constexpr float INV_TAU     = 25.0f;  // 1/0.04
constexpr float INV_TAU_STU = 10.0f;  // 1/0.1
}

typedef __attribute__((ext_vector_type(8))) short bf16x8;
typedef __attribute__((ext_vector_type(4))) float f32x4;

__device__ __forceinline__ float wave_max(float v) {
  for (int o = 32; o; o >>= 1) v = fmaxf(v, __shfl_xor(v, o));
  return v;
}
__device__ __forceinline__ float wave_sum(float v) {
  for (int o = 32; o; o >>= 1) v += __shfl_xor(v, o);
  return v;
}
__device__ __forceinline__ short f2bf(float x) {  // RNE fp32->bf16
  unsigned u = __float_as_uint(x);
  u = u + 0x7FFFu + ((u >> 16) & 1u);
  return (short)(u >> 16);
}
__device__ __forceinline__ float bf2f(unsigned short h) {
  return __uint_as_float(((unsigned)h) << 16);
}

// ---------------------------------------------------------------------------
// kmain: one block per teacher batch bt (student bs = bt ^ 256).
// Phases: uq-detect -> stage bf16 swizzled s_fea/t_fea tiles + t_region pass
// (out_tr write + softmax stats) + cls term -> t-row norms -> MFMA sim +
// in-register argmax -> loss rows (teacher rows re-gathered from L2).
// LDS ~65 KB -> 2 blocks/CU.
// ---------------------------------------------------------------------------
__global__ __launch_bounds__(256, 2) void kmain(
    const float* __restrict__ s_cls_out,
    const float* __restrict__ s_region_out,
    const float* __restrict__ s_fea,
    const float* __restrict__ t_cls_out,
    const float* __restrict__ t_region_out,
    const float* __restrict__ t_fea,
    const float* __restrict__ queue_all,
    const float* __restrict__ queue_grid_all,
    const float* __restrict__ center,
    const float* __restrict__ center_grid,
    const int* __restrict__ concept_idx,
    const int* __restrict__ pos_idx,
    const unsigned char* __restrict__ uq,
    float* __restrict__ out_tc,
    float* __restrict__ out_tr,
    float* __restrict__ block_part) {
  __shared__ __align__(16) unsigned short sfb[NP * Dv];  // 32 KB bf16, swizzled
  __shared__ __align__(16) unsigned short tfb[NP * Dv];  // 32 KB
  __shared__ float stats[NR * 2];
  __shared__ float rinv[NP];
  __shared__ int ms_lds[NR];
  __shared__ int flags4[4];
  __shared__ float red[4];

  const int bt = blockIdx.x, bs = bt ^ 256;
  const int tid = threadIdx.x, lane = tid & 63, wave = tid >> 6;

  // ---- use_queue bool(1B)-vs-int32 layout detection (512B covers both) ----
  {
    unsigned w = ((const unsigned*)uq)[tid & 127];
    int a = __any((w & 0xFFFFFF00u) != 0);
    if (lane == 0) flags4[wave] = a;
  }
  __syncthreads();
  const bool isbool = (flags4[0] | flags4[1] | flags4[2] | flags4[3]) != 0;
  const int uqv = isbool ? (int)uq[bt] : ((const int*)uq)[bt];
  const bool use = uqv != 0;
  const size_t qoff = (size_t)concept_idx[bt] * KQ + (size_t)pos_idx[bt];
  const float* qg = queue_grid_all + qoff * (size_t)(2 * NR) * Dv;
  const float* sfsrc = s_fea + (size_t)bs * NR * Dv;
  const float* tfsrc = use ? (qg + (size_t)NR * Dv) : (t_fea + (size_t)bt * NR * Dv);

  // ---- stage bf16 tiles, 16B-chunk XOR swizzle: chunk c of row r -> c^(r&7)
  for (int q = tid; q < NP * 32; q += 256) {
    const int r = q >> 5, c = q & 31;
    const int dst = r * Dv + ((c ^ (r & 7)) << 3);
    bf16x8 pa = {0, 0, 0, 0, 0, 0, 0, 0};
    bf16x8 pb = {0, 0, 0, 0, 0, 0, 0, 0};
    if (r < NR) {
      const float* ps = sfsrc + (size_t)r * Dv + c * 8;
      const float* pt = tfsrc + (size_t)r * Dv + c * 8;
      float4 s0 = *(const float4*)ps, s1 = *(const float4*)(ps + 4);
      float4 t0 = *(const float4*)pt, t1 = *(const float4*)(pt + 4);
      pa[0] = f2bf(s0.x); pa[1] = f2bf(s0.y); pa[2] = f2bf(s0.z); pa[3] = f2bf(s0.w);
      pa[4] = f2bf(s1.x); pa[5] = f2bf(s1.y); pa[6] = f2bf(s1.z); pa[7] = f2bf(s1.w);
      pb[0] = f2bf(t0.x); pb[1] = f2bf(t0.y); pb[2] = f2bf(t0.z); pb[3] = f2bf(t0.w);
      pb[4] = f2bf(t1.x); pb[5] = f2bf(t1.y); pb[6] = f2bf(t1.z); pb[7] = f2bf(t1.w);
    }
    *(bf16x8*)&sfb[dst] = pa;
    *(bf16x8*)&tfb[dst] = pb;
  }

  // ---- t_region pass: dequeue write + per-row teacher softmax stats ----
  const float4 cg4 = *(const float4*)(center_grid + lane * 4);
  for (int r = wave; r < NR; r += 4) {
    const float* src = use ? (qg + (size_t)r * Dv)
                           : (t_region_out + ((size_t)bt * NR + r) * Dv);
    float4 v = *(const float4*)(src + lane * 4);
    float* o = out_tr + ((size_t)bt * NR + r) * Dv + lane * 4;  // 4B-aligned only
    o[0] = v.x; o[1] = v.y; o[2] = v.z; o[3] = v.w;
    float x0 = (v.x - cg4.x) * INV_TAU, x1 = (v.y - cg4.y) * INV_TAU;
    float x2 = (v.z - cg4.z) * INV_TAU, x3 = (v.w - cg4.w) * INV_TAU;
    float m = wave_max(fmaxf(fmaxf(x0, x1), fmaxf(x2, x3)));
    float e = wave_sum(expf(x0 - m) + expf(x1 - m) + expf(x2 - m) + expf(x3 - m));
    if (lane == 0) { stats[r * 2] = m; stats[r * 2 + 1] = e; }
  }

  // ---- cls KL term (wave 0 only; wave-local, no barrier needed) ----
  float cls_val = 0.f;
  if (wave == 0) {
    const float* tcsrc = use ? (queue_all + qoff * Dv) : (t_cls_out + (size_t)bt * Dv);
    float4 t4 = *(const float4*)(tcsrc + lane * 4);
    float* otc = out_tc + (size_t)bt * Dv + lane * 4;  // 4B-aligned only
    otc[0] = t4.x; otc[1] = t4.y; otc[2] = t4.z; otc[3] = t4.w;
    float4 c4 = *(const float4*)(center + lane * 4);
    float x0 = (t4.x - c4.x) * INV_TAU, x1 = (t4.y - c4.y) * INV_TAU;
    float x2 = (t4.z - c4.z) * INV_TAU, x3 = (t4.w - c4.w) * INV_TAU;
    float M = wave_max(fmaxf(fmaxf(x0, x1), fmaxf(x2, x3)));
    float e0 = expf(x0 - M), e1 = expf(x1 - M), e2 = expf(x2 - M), e3 = expf(x3 - M);
    float S = wave_sum(e0 + e1 + e2 + e3);
    float4 s4 = *(const float4*)(s_cls_out + (size_t)bs * Dv + lane * 4);
    float z0 = s4.x * INV_TAU, z1 = s4.y * INV_TAU;
    float z2 = s4.z * INV_TAU, z3 = s4.w * INV_TAU;
    float M2 = wave_max(fmaxf(fmaxf(z0, z1), fmaxf(z2, z3)));
    float S2 = wave_sum(expf(z0 - M2) + expf(z1 - M2) + expf(z2 - M2) + expf(z3 - M2));
    float lse = M2 + logf(S2);
    cls_val = 0.5f * wave_sum(e0 * (lse - z0) + e1 * (lse - z1) +
                              e2 * (lse - z2) + e3 * (lse - z3)) / S;
  }
  __syncthreads();

  // ---- teacher row inverse norms (from staged bf16; masked rows are zero) --
  for (int r = wave; r < NP; r += 4) {
    const int ch = (lane >> 1) ^ (r & 7);
    const unsigned short* p = &tfb[r * Dv + ch * 8 + (lane & 1) * 4];
    float a0 = bf2f(p[0]), a1 = bf2f(p[1]), a2 = bf2f(p[2]), a3 = bf2f(p[3]);
    float ss = wave_sum(a0 * a0 + a1 * a1 + a2 * a2 + a3 * a3);
    if (lane == 0) rinv[r] = 1.0f / fmaxf(sqrtf(ss), 1e-12f);
  }
  __syncthreads();

  // ---- MFMA sim (64x64 padded) + in-register argmax over m ----
  // A-frag lane map: row = lane&15, k = (lane>>4)*8 + j. B[k][m] = T[m][k] ->
  // same row-major read from tfb. D: col(m)=lane&15, row(n)=(lane>>4)*4+reg.
  {
    f32x4 acc[4];
#pragma unroll
    for (int mb = 0; mb < 4; mb++) acc[mb] = (f32x4){0.f, 0.f, 0.f, 0.f};
    const int rsel = lane & 15, g = lane >> 4, rsw = lane & 7;
    const int rowA = (wave << 4) + rsel;
#pragma unroll
    for (int kk = 0; kk < 8; kk++) {
      const int ch = (kk * 4 + g) ^ rsw;  // rowA&7 == rowB&7 == lane&7
      bf16x8 a = *(const bf16x8*)&sfb[rowA * Dv + (ch << 3)];
#pragma unroll
      for (int mb = 0; mb < 4; mb++) {
        bf16x8 b = *(const bf16x8*)&tfb[((mb << 4) + rsel) * Dv + (ch << 3)];
        acc[mb] = __builtin_amdgcn_mfma_f32_16x16x32_bf16(a, b, acc[mb], 0, 0, 0);
      }
    }
    // per-reg (=per-n) argmax: first over mb (m ascending, strict >), then
    // across the 16-lane group with (val, smaller-index) tie-break.
    float bv[4] = {-INFINITY, -INFINITY, -INFINITY, -INFINITY};
    int bm[4] = {999, 999, 999, 999};
#pragma unroll
    for (int mb = 0; mb < 4; mb++) {
      const int m = (mb << 4) + rsel;
      if (m < NR) {
        const float rv = rinv[m];
#pragma unroll
        for (int r = 0; r < 4; r++) {
          float s = acc[mb][r] * rv;
          if (s > bv[r]) { bv[r] = s; bm[r] = m; }
        }
      }
    }
#pragma unroll
    for (int o = 1; o < 16; o <<= 1) {
#pragma unroll
      for (int r = 0; r < 4; r++) {
        float ov = __shfl_xor(bv[r], o);
        int om = __shfl_xor(bm[r], o);
        if (ov > bv[r] || (ov == bv[r] && om < bm[r])) { bv[r] = ov; bm[r] = om; }
      }
    }
    if (rsel == 0) {
#pragma unroll
      for (int r = 0; r < 4; r++) {
        const int n = (wave << 4) + (g << 2) + r;
        if (n < NR) ms_lds[n] = bm[r];
      }
    }
  }
  __syncthreads();

  // ---- loss rows: wave-per-n; teacher row gather is L2-hot (read in stage) -
  float gacc = 0.f;
  for (int n = wave; n < NR; n += 4) {
    float4 y4 = *(const float4*)(s_region_out + ((size_t)bs * NR + n) * Dv + lane * 4);
    float y0 = y4.x * INV_TAU_STU, y1 = y4.y * INV_TAU_STU;
    float y2 = y4.z * INV_TAU_STU, y3 = y4.w * INV_TAU_STU;
    float smax = wave_max(fmaxf(fmaxf(y0, y1), fmaxf(y2, y3)));
    float ssum = wave_sum(expf(y0 - smax) + expf(y1 - smax) +
                          expf(y2 - smax) + expf(y3 - smax));
    float lse = smax + logf(ssum);
    const int ms = ms_lds[n];
    const float* trow = use ? (qg + (size_t)ms * Dv)
                            : (t_region_out + ((size_t)bt * NR + ms) * Dv);
    float4 v4 = *(const float4*)(trow + lane * 4);
    float x0 = (v4.x - cg4.x) * INV_TAU, x1 = (v4.y - cg4.y) * INV_TAU;
    float x2 = (v4.z - cg4.z) * INV_TAU, x3 = (v4.w - cg4.w) * INV_TAU;
    float tmax = stats[ms * 2], tsum = stats[ms * 2 + 1];
    float part = wave_sum(expf(x0 - tmax) * (lse - y0) + expf(x1 - tmax) * (lse - y1) +
                          expf(x2 - tmax) * (lse - y2) + expf(x3 - tmax) * (lse - y3));
    gacc += part / tsum;
  }
  if (lane == 0) red[wave] = gacc;
  __syncthreads();
  if (tid == 0)
    block_part[bt] = cls_val + (0.5f / 49.0f) * (red[0] + red[1] + red[2] + red[3]);
}

// ---------------------------------------------------------------------------
// k4: deterministic final reduction. out[0] = sum(block_part)/512
// ---------------------------------------------------------------------------
__global__ __launch_bounds__(256) void k4_final(const float* __restrict__ block_part,
                                                float* __restrict__ out) {
  __shared__ float red[4];
  const int tid = threadIdx.x, lane = tid & 63, wave = tid >> 6;
  float a = block_part[tid] + block_part[tid + 256];
  a = wave_sum(a);
  if (lane == 0) red[wave] = a;
  __syncthreads();
  if (tid == 0)
    out[0] = (red[0] + red[1] + red[2] + red[3]) * (1.0f / 512.0f);
}

extern "C" void kernel_launch(void* const* d_in, const int* in_sizes, int n_in,
                              void* d_out, int out_size, void* d_ws, size_t ws_size,
                              hipStream_t stream) {
  (void)in_sizes; (void)n_in; (void)out_size; (void)ws_size;
  const float* s_cls_out      = (const float*)d_in[0];
  const float* s_region_out   = (const float*)d_in[1];
  const float* s_fea          = (const float*)d_in[2];
  const float* t_cls_out      = (const float*)d_in[3];
  const float* t_region_out   = (const float*)d_in[4];
  const float* t_fea          = (const float*)d_in[5];
  const float* queue_all      = (const float*)d_in[6];
  const float* queue_grid_all = (const float*)d_in[7];
  const float* center         = (const float*)d_in[8];
  const float* center_grid    = (const float*)d_in[9];
  const int* concept_idx      = (const int*)d_in[10];
  const int* pos_idx          = (const int*)d_in[11];
  const unsigned char* use_q  = (const unsigned char*)d_in[12];

  float* out    = (float*)d_out;
  float* out_tc = out + 1;                 // 512*256
  float* out_tr = out + 1 + B2v * Dv;      // 25088*256

  float* block_part = (float*)d_ws;        // 512 floats

  kmain<<<B2v, 256, 0, stream>>>(s_cls_out, s_region_out, s_fea, t_cls_out,
                                 t_region_out, t_fea, queue_all, queue_grid_all,
                                 center, center_grid, concept_idx, pos_idx,
                                 use_q, out_tc, out_tr, block_part);
  k4_final<<<1, 256, 0, stream>>>(block_part, out);
}

// Round 5
// 39.484 us; speedup vs baseline: 5.5373x; 1.3433x over previous
//
#include <hip/hip_runtime.h>
#include <math.h>

namespace {
constexpr int B2v = 512;
constexpr int NR  = 49;     // regions per view
constexpr int NP  = 64;     // padded rows for MFMA tile
constexpr int Dv  = 256;    // feature dim
constexpr int KQ  = 128;    // queue K
constexpr float INV_TAU     = 25.0f;  // 1/0.04
constexpr float INV_TAU_STU = 10.0f;  // 1/0.1
}

typedef __attribute__((ext_vector_type(8))) short bf16x8;
typedef __attribute__((ext_vector_type(4))) float f32x4;

__device__ __forceinline__ float wave_max(float v) {
  for (int o = 32; o; o >>= 1) v = fmaxf(v, __shfl_xor(v, o));
  return v;
}
__device__ __forceinline__ float wave_sum(float v) {
  for (int o = 32; o; o >>= 1) v += __shfl_xor(v, o);
  return v;
}
__device__ __forceinline__ short f2bf(float x) {  // RNE fp32->bf16
  unsigned u = __float_as_uint(x);
  u = u + 0x7FFFu + ((u >> 16) & 1u);
  return (short)(u >> 16);
}
__device__ __forceinline__ float bf2f(unsigned short h) {
  return __uint_as_float(((unsigned)h) << 16);
}

// ---------------------------------------------------------------------------
// kmain: one 512-thread block per teacher batch bt (student bs = bt ^ 256).
// 8 waves -> 16 waves/CU (4/SIMD) at 2 blocks/CU (LDS ~65 KB).
// All fresh-HBM streams batched up front (stage tiles, t_region pass,
// s_region y/lse rows held in registers, cls term); after the MFMA+argmax
// only an L2-hot teacher-row gather remains. block_part via plain stores;
// final reduction is a separate tiny kernel (no cross-call d_ws state).
// ---------------------------------------------------------------------------
__global__ __launch_bounds__(512, 4) void kmain(
    const float* __restrict__ s_cls_out,
    const float* __restrict__ s_region_out,
    const float* __restrict__ s_fea,
    const float* __restrict__ t_cls_out,
    const float* __restrict__ t_region_out,
    const float* __restrict__ t_fea,
    const float* __restrict__ queue_all,
    const float* __restrict__ queue_grid_all,
    const float* __restrict__ center,
    const float* __restrict__ center_grid,
    const int* __restrict__ concept_idx,
    const int* __restrict__ pos_idx,
    const unsigned char* __restrict__ uq,
    float* __restrict__ out_tc,
    float* __restrict__ out_tr,
    float* __restrict__ block_part) {
  __shared__ __align__(16) unsigned short sfb[NP * Dv];  // 32 KB bf16, swizzled
  __shared__ __align__(16) unsigned short tfb[NP * Dv];  // 32 KB
  __shared__ float stats[NR * 2];
  __shared__ float rinv[NP];
  __shared__ int ms_lds[NR];
  __shared__ int flags8[8];
  __shared__ float red[8];
  __shared__ float cls_s;

  const int bt = blockIdx.x, bs = bt ^ 256;
  const int tid = threadIdx.x, lane = tid & 63, wave = tid >> 6;

  // ---- use_queue bool(1B)-vs-int32 layout detection (512B covers both) ----
  {
    unsigned w = ((const unsigned*)uq)[tid & 127];
    int a = __any((w & 0xFFFFFF00u) != 0);
    if (lane == 0) flags8[wave] = a;
  }
  __syncthreads();
  int fl = flags8[0] | flags8[1] | flags8[2] | flags8[3] |
           flags8[4] | flags8[5] | flags8[6] | flags8[7];
  const bool isbool = fl != 0;
  const int uqv = isbool ? (int)uq[bt] : ((const int*)uq)[bt];
  const bool use = uqv != 0;
  const size_t qoff = (size_t)concept_idx[bt] * KQ + (size_t)pos_idx[bt];
  const float* qg = queue_grid_all + qoff * (size_t)(2 * NR) * Dv;
  const float* sfsrc = s_fea + (size_t)bs * NR * Dv;
  const float* tfsrc = use ? (qg + (size_t)NR * Dv) : (t_fea + (size_t)bt * NR * Dv);

  // ==== batched fresh-HBM streams ====

  // (a) stage bf16 tiles, 16B-chunk XOR swizzle: chunk c of row r -> c^(r&7)
  for (int q = tid; q < NP * 32; q += 512) {
    const int r = q >> 5, c = q & 31;
    const int dst = r * Dv + ((c ^ (r & 7)) << 3);
    bf16x8 pa = {0, 0, 0, 0, 0, 0, 0, 0};
    bf16x8 pb = {0, 0, 0, 0, 0, 0, 0, 0};
    if (r < NR) {
      const float* ps = sfsrc + (size_t)r * Dv + c * 8;
      const float* pt = tfsrc + (size_t)r * Dv + c * 8;
      float4 s0 = *(const float4*)ps, s1 = *(const float4*)(ps + 4);
      float4 t0 = *(const float4*)pt, t1 = *(const float4*)(pt + 4);
      pa[0] = f2bf(s0.x); pa[1] = f2bf(s0.y); pa[2] = f2bf(s0.z); pa[3] = f2bf(s0.w);
      pa[4] = f2bf(s1.x); pa[5] = f2bf(s1.y); pa[6] = f2bf(s1.z); pa[7] = f2bf(s1.w);
      pb[0] = f2bf(t0.x); pb[1] = f2bf(t0.y); pb[2] = f2bf(t0.z); pb[3] = f2bf(t0.w);
      pb[4] = f2bf(t1.x); pb[5] = f2bf(t1.y); pb[6] = f2bf(t1.z); pb[7] = f2bf(t1.w);
    }
    *(bf16x8*)&sfb[dst] = pa;
    *(bf16x8*)&tfb[dst] = pb;
  }

  // (b) s_region y rows -> registers (wave-interleaved n), lse per row
  float4 yv[7];
  float lsev[7];
#pragma unroll
  for (int j = 0; j < 7; j++) {
    const int n = wave + 8 * j;
    if (n < NR) {
      float4 y4 = *(const float4*)(s_region_out + ((size_t)bs * NR + n) * Dv + lane * 4);
      y4.x *= INV_TAU_STU; y4.y *= INV_TAU_STU;
      y4.z *= INV_TAU_STU; y4.w *= INV_TAU_STU;
      float smax = wave_max(fmaxf(fmaxf(y4.x, y4.y), fmaxf(y4.z, y4.w)));
      float ssum = wave_sum(expf(y4.x - smax) + expf(y4.y - smax) +
                            expf(y4.z - smax) + expf(y4.w - smax));
      yv[j] = y4;
      lsev[j] = smax + logf(ssum);
    }
  }

  // (c) t_region pass: dequeue write + per-row teacher softmax stats
  const float4 cg4 = *(const float4*)(center_grid + lane * 4);
  for (int r = wave; r < NR; r += 8) {
    const float* src = use ? (qg + (size_t)r * Dv)
                           : (t_region_out + ((size_t)bt * NR + r) * Dv);
    float4 v = *(const float4*)(src + lane * 4);
    float* o = out_tr + ((size_t)bt * NR + r) * Dv + lane * 4;  // 4B-aligned only
    o[0] = v.x; o[1] = v.y; o[2] = v.z; o[3] = v.w;
    float x0 = (v.x - cg4.x) * INV_TAU, x1 = (v.y - cg4.y) * INV_TAU;
    float x2 = (v.z - cg4.z) * INV_TAU, x3 = (v.w - cg4.w) * INV_TAU;
    float m = wave_max(fmaxf(fmaxf(x0, x1), fmaxf(x2, x3)));
    float e = wave_sum(expf(x0 - m) + expf(x1 - m) + expf(x2 - m) + expf(x3 - m));
    if (lane == 0) { stats[r * 2] = m; stats[r * 2 + 1] = e; }
  }

  // (d) cls KL term (wave 7; wave-local)
  if (wave == 7) {
    const float* tcsrc = use ? (queue_all + qoff * Dv) : (t_cls_out + (size_t)bt * Dv);
    float4 t4 = *(const float4*)(tcsrc + lane * 4);
    float* otc = out_tc + (size_t)bt * Dv + lane * 4;  // 4B-aligned only
    otc[0] = t4.x; otc[1] = t4.y; otc[2] = t4.z; otc[3] = t4.w;
    float4 c4 = *(const float4*)(center + lane * 4);
    float x0 = (t4.x - c4.x) * INV_TAU, x1 = (t4.y - c4.y) * INV_TAU;
    float x2 = (t4.z - c4.z) * INV_TAU, x3 = (t4.w - c4.w) * INV_TAU;
    float M = wave_max(fmaxf(fmaxf(x0, x1), fmaxf(x2, x3)));
    float e0 = expf(x0 - M), e1 = expf(x1 - M), e2 = expf(x2 - M), e3 = expf(x3 - M);
    float S = wave_sum(e0 + e1 + e2 + e3);
    float4 s4 = *(const float4*)(s_cls_out + (size_t)bs * Dv + lane * 4);
    float z0 = s4.x * INV_TAU, z1 = s4.y * INV_TAU;
    float z2 = s4.z * INV_TAU, z3 = s4.w * INV_TAU;
    float M2 = wave_max(fmaxf(fmaxf(z0, z1), fmaxf(z2, z3)));
    float S2 = wave_sum(expf(z0 - M2) + expf(z1 - M2) + expf(z2 - M2) + expf(z3 - M2));
    float lse = M2 + logf(S2);
    float cv = 0.5f * wave_sum(e0 * (lse - z0) + e1 * (lse - z1) +
                               e2 * (lse - z2) + e3 * (lse - z3)) / S;
    if (lane == 0) cls_s = cv;
  }
  __syncthreads();

  // ---- teacher row inverse norms (from staged bf16; masked rows are zero) --
  for (int r = wave; r < NP; r += 8) {
    const int ch = (lane >> 1) ^ (r & 7);
    const unsigned short* p = &tfb[r * Dv + ch * 8 + (lane & 1) * 4];
    float a0 = bf2f(p[0]), a1 = bf2f(p[1]), a2 = bf2f(p[2]), a3 = bf2f(p[3]);
    float ss = wave_sum(a0 * a0 + a1 * a1 + a2 * a2 + a3 * a3);
    if (lane == 0) rinv[r] = 1.0f / fmaxf(sqrtf(ss), 1e-12f);
  }
  __syncthreads();

  // ---- MFMA sim (64x64 padded, waves 0-3) + in-register argmax over m ----
  if (wave < 4) {
    f32x4 acc[4];
#pragma unroll
    for (int mb = 0; mb < 4; mb++) acc[mb] = (f32x4){0.f, 0.f, 0.f, 0.f};
    const int rsel = lane & 15, g = lane >> 4, rsw = lane & 7;
    const int rowA = (wave << 4) + rsel;
#pragma unroll
    for (int kk = 0; kk < 8; kk++) {
      const int ch = (kk * 4 + g) ^ rsw;  // rowA&7 == rowB&7 == lane&7
      bf16x8 a = *(const bf16x8*)&sfb[rowA * Dv + (ch << 3)];
#pragma unroll
      for (int mb = 0; mb < 4; mb++) {
        bf16x8 b = *(const bf16x8*)&tfb[((mb << 4) + rsel) * Dv + (ch << 3)];
        acc[mb] = __builtin_amdgcn_mfma_f32_16x16x32_bf16(a, b, acc[mb], 0, 0, 0);
      }
    }
    float bv[4] = {-INFINITY, -INFINITY, -INFINITY, -INFINITY};
    int bm[4] = {999, 999, 999, 999};
#pragma unroll
    for (int mb = 0; mb < 4; mb++) {
      const int m = (mb << 4) + rsel;
      if (m < NR) {
        const float rv = rinv[m];
#pragma unroll
        for (int r = 0; r < 4; r++) {
          float s = acc[mb][r] * rv;
          if (s > bv[r]) { bv[r] = s; bm[r] = m; }
        }
      }
    }
#pragma unroll
    for (int o = 1; o < 16; o <<= 1) {
#pragma unroll
      for (int r = 0; r < 4; r++) {
        float ov = __shfl_xor(bv[r], o);
        int om = __shfl_xor(bm[r], o);
        if (ov > bv[r] || (ov == bv[r] && om < bm[r])) { bv[r] = ov; bm[r] = om; }
      }
    }
    if (rsel == 0) {
#pragma unroll
      for (int r = 0; r < 4; r++) {
        const int n = (wave << 4) + (g << 2) + r;
        if (n < NR) ms_lds[n] = bm[r];
      }
    }
  }
  __syncthreads();

  // ---- loss rows: y/lse in regs; teacher gather is L2-hot; batch issues ----
  float4 tv[7];
  int msj[7];
#pragma unroll
  for (int j = 0; j < 7; j++) {
    const int n = wave + 8 * j;
    if (n < NR) {
      const int ms = ms_lds[n];
      msj[j] = ms;
      const float* trow = use ? (qg + (size_t)ms * Dv)
                              : (t_region_out + ((size_t)bt * NR + ms) * Dv);
      tv[j] = *(const float4*)(trow + lane * 4);
    }
  }
  float gacc = 0.f;
#pragma unroll
  for (int j = 0; j < 7; j++) {
    const int n = wave + 8 * j;
    if (n < NR) {
      const int ms = msj[j];
      const float4 v4 = tv[j];
      const float4 y4 = yv[j];
      const float lse = lsev[j];
      float x0 = (v4.x - cg4.x) * INV_TAU, x1 = (v4.y - cg4.y) * INV_TAU;
      float x2 = (v4.z - cg4.z) * INV_TAU, x3 = (v4.w - cg4.w) * INV_TAU;
      float tmax = stats[ms * 2], tsum = stats[ms * 2 + 1];
      float part = wave_sum(expf(x0 - tmax) * (lse - y4.x) +
                            expf(x1 - tmax) * (lse - y4.y) +
                            expf(x2 - tmax) * (lse - y4.z) +
                            expf(x3 - tmax) * (lse - y4.w));
      gacc += part / tsum;
    }
  }
  if (lane == 0) red[wave] = gacc;
  __syncthreads();
  if (tid == 0) {
    float s = red[0] + red[1] + red[2] + red[3] +
              red[4] + red[5] + red[6] + red[7];
    block_part[bt] = cls_s + (0.5f / 49.0f) * s;
  }
}

// ---------------------------------------------------------------------------
// k4: deterministic final reduction. out[0] = sum(block_part)/512
// ---------------------------------------------------------------------------
__global__ __launch_bounds__(256) void k4_final(const float* __restrict__ block_part,
                                                float* __restrict__ out) {
  __shared__ float red[4];
  const int tid = threadIdx.x, lane = tid & 63, wave = tid >> 6;
  float a = block_part[tid] + block_part[tid + 256];
  a = wave_sum(a);
  if (lane == 0) red[wave] = a;
  __syncthreads();
  if (tid == 0)
    out[0] = (red[0] + red[1] + red[2] + red[3]) * (1.0f / 512.0f);
}

extern "C" void kernel_launch(void* const* d_in, const int* in_sizes, int n_in,
                              void* d_out, int out_size, void* d_ws, size_t ws_size,
                              hipStream_t stream) {
  (void)in_sizes; (void)n_in; (void)out_size; (void)ws_size;
  const float* s_cls_out      = (const float*)d_in[0];
  const float* s_region_out   = (const float*)d_in[1];
  const float* s_fea          = (const float*)d_in[2];
  const float* t_cls_out      = (const float*)d_in[3];
  const float* t_region_out   = (const float*)d_in[4];
  const float* t_fea          = (const float*)d_in[5];
  const float* queue_all      = (const float*)d_in[6];
  const float* queue_grid_all = (const float*)d_in[7];
  const float* center         = (const float*)d_in[8];
  const float* center_grid    = (const float*)d_in[9];
  const int* concept_idx      = (const int*)d_in[10];
  const int* pos_idx          = (const int*)d_in[11];
  const unsigned char* use_q  = (const unsigned char*)d_in[12];

  float* out    = (float*)d_out;
  float* out_tc = out + 1;                 // 512*256
  float* out_tr = out + 1 + B2v * Dv;      // 25088*256

  float* block_part = (float*)d_ws;        // 512 floats

  kmain<<<B2v, 512, 0, stream>>>(s_cls_out, s_region_out, s_fea, t_cls_out,
                                 t_region_out, t_fea, queue_all, queue_grid_all,
                                 center, center_grid, concept_idx, pos_idx,
                                 use_q, out_tc, out_tr, block_part);
  k4_final<<<1, 256, 0, stream>>>(block_part, out);
}

// Round 6
// 38.280 us; speedup vs baseline: 5.7114x; 1.0314x over previous
//
#include <hip/hip_runtime.h>
#include <math.h>

namespace {
constexpr int B2v = 512;
constexpr int NR  = 49;     // regions per view
constexpr int NP  = 64;     // padded rows for MFMA tile
constexpr int Dv  = 256;    // feature dim
constexpr int KQ  = 128;    // queue K
constexpr float INV_TAU     = 25.0f;  // 1/0.04
constexpr float INV_TAU_STU = 10.0f;  // 1/0.1
}

typedef __attribute__((ext_vector_type(8))) short bf16x8;
typedef __attribute__((ext_vector_type(4))) float f32x4;

__device__ __forceinline__ float wave_max(float v) {
  for (int o = 32; o; o >>= 1) v = fmaxf(v, __shfl_xor(v, o));
  return v;
}
__device__ __forceinline__ float wave_sum(float v) {
  for (int o = 32; o; o >>= 1) v += __shfl_xor(v, o);
  return v;
}
__device__ __forceinline__ short f2bf(float x) {  // RNE fp32->bf16
  unsigned u = __float_as_uint(x);
  u = u + 0x7FFFu + ((u >> 16) & 1u);
  return (short)(u >> 16);
}
__device__ __forceinline__ float bf2f(unsigned short h) {
  return __uint_as_float(((unsigned)h) << 16);
}

// ---------------------------------------------------------------------------
// kmain: one 512-thread block per teacher batch bt (student bs = bt ^ 256).
// 8 waves -> 16 waves/CU (4/SIMD) at 2 blocks/CU (LDS ~67 KB).
// Changes vs prev round: (1) no prefix barrier — per-wave uq detection,
// s-side loads issue before uq resolution; (2) MFMA split across all 8 waves
// (A-row-block x m-half), per-half argmax candidates combined inline in the
// loss phase (tie -> half 0 = lower m, preserving jnp.argmax first-index).
// ---------------------------------------------------------------------------
__global__ __launch_bounds__(512, 4) void kmain(
    const float* __restrict__ s_cls_out,
    const float* __restrict__ s_region_out,
    const float* __restrict__ s_fea,
    const float* __restrict__ t_cls_out,
    const float* __restrict__ t_region_out,
    const float* __restrict__ t_fea,
    const float* __restrict__ queue_all,
    const float* __restrict__ queue_grid_all,
    const float* __restrict__ center,
    const float* __restrict__ center_grid,
    const int* __restrict__ concept_idx,
    const int* __restrict__ pos_idx,
    const unsigned char* __restrict__ uq,
    float* __restrict__ out_tc,
    float* __restrict__ out_tr,
    float* __restrict__ block_part) {
  __shared__ __align__(16) unsigned short sfb[NP * Dv];  // 32 KB bf16, swizzled
  __shared__ __align__(16) unsigned short tfb[NP * Dv];  // 32 KB
  __shared__ float stats[NR * 2];
  __shared__ float rinv[NP];
  __shared__ float cand_v[2][NP];
  __shared__ int   cand_m[2][NP];
  __shared__ float red[8];
  __shared__ float cls_s;

  const int bt = blockIdx.x, bs = bt ^ 256;
  const int tid = threadIdx.x, lane = tid & 63, wave = tid >> 6;

  // ---- hoisted scalar/index loads (issue first, consume later) ----
  const int ci = concept_idx[bt], pi = pos_idx[bt];
  const uint2 w2 = ((const uint2*)uq)[lane];  // 512 B, legal in both layouts
  const float* sfsrc = s_fea + (size_t)bs * NR * Dv;

  // (a1) stage s-side bf16 tile (uq-independent; issues immediately)
  for (int q = tid; q < NP * 32; q += 512) {
    const int r = q >> 5, c = q & 31;
    const int dst = r * Dv + ((c ^ (r & 7)) << 3);
    bf16x8 pa = {0, 0, 0, 0, 0, 0, 0, 0};
    if (r < NR) {
      const float* ps = sfsrc + (size_t)r * Dv + c * 8;
      float4 s0 = *(const float4*)ps, s1 = *(const float4*)(ps + 4);
      pa[0] = f2bf(s0.x); pa[1] = f2bf(s0.y); pa[2] = f2bf(s0.z); pa[3] = f2bf(s0.w);
      pa[4] = f2bf(s1.x); pa[5] = f2bf(s1.y); pa[6] = f2bf(s1.z); pa[7] = f2bf(s1.w);
    }
    *(bf16x8*)&sfb[dst] = pa;
  }

  // (b) s_region y rows -> registers (wave-interleaved n), lse per row
  float4 yv[7];
  float lsev[7];
#pragma unroll
  for (int j = 0; j < 7; j++) {
    const int n = wave + 8 * j;
    if (n < NR) {
      float4 y4 = *(const float4*)(s_region_out + ((size_t)bs * NR + n) * Dv + lane * 4);
      y4.x *= INV_TAU_STU; y4.y *= INV_TAU_STU;
      y4.z *= INV_TAU_STU; y4.w *= INV_TAU_STU;
      float smax = wave_max(fmaxf(fmaxf(y4.x, y4.y), fmaxf(y4.z, y4.w)));
      float ssum = wave_sum(expf(y4.x - smax) + expf(y4.y - smax) +
                            expf(y4.z - smax) + expf(y4.w - smax));
      yv[j] = y4;
      lsev[j] = smax + logf(ssum);
    }
  }

  // ---- per-wave use_queue layout detection (no barrier, no LDS) ----
  const bool isbool = __any(((w2.x | w2.y) & 0xFFFFFF00u) != 0) != 0;
  const int uqv = isbool ? (int)uq[bt] : ((const int*)uq)[bt];
  const bool use = uqv != 0;
  const size_t qoff = (size_t)ci * KQ + (size_t)pi;
  const float* qg = queue_grid_all + qoff * (size_t)(2 * NR) * Dv;
  const float* tfsrc = use ? (qg + (size_t)NR * Dv) : (t_fea + (size_t)bt * NR * Dv);

  // (a2) stage t-side bf16 tile
  for (int q = tid; q < NP * 32; q += 512) {
    const int r = q >> 5, c = q & 31;
    const int dst = r * Dv + ((c ^ (r & 7)) << 3);
    bf16x8 pb = {0, 0, 0, 0, 0, 0, 0, 0};
    if (r < NR) {
      const float* pt = tfsrc + (size_t)r * Dv + c * 8;
      float4 t0 = *(const float4*)pt, t1 = *(const float4*)(pt + 4);
      pb[0] = f2bf(t0.x); pb[1] = f2bf(t0.y); pb[2] = f2bf(t0.z); pb[3] = f2bf(t0.w);
      pb[4] = f2bf(t1.x); pb[5] = f2bf(t1.y); pb[6] = f2bf(t1.z); pb[7] = f2bf(t1.w);
    }
    *(bf16x8*)&tfb[dst] = pb;
  }

  // (c) t_region pass: dequeue write + per-row teacher softmax stats
  const float4 cg4 = *(const float4*)(center_grid + lane * 4);
  for (int r = wave; r < NR; r += 8) {
    const float* src = use ? (qg + (size_t)r * Dv)
                           : (t_region_out + ((size_t)bt * NR + r) * Dv);
    float4 v = *(const float4*)(src + lane * 4);
    float* o = out_tr + ((size_t)bt * NR + r) * Dv + lane * 4;  // 4B-aligned only
    o[0] = v.x; o[1] = v.y; o[2] = v.z; o[3] = v.w;
    float x0 = (v.x - cg4.x) * INV_TAU, x1 = (v.y - cg4.y) * INV_TAU;
    float x2 = (v.z - cg4.z) * INV_TAU, x3 = (v.w - cg4.w) * INV_TAU;
    float m = wave_max(fmaxf(fmaxf(x0, x1), fmaxf(x2, x3)));
    float e = wave_sum(expf(x0 - m) + expf(x1 - m) + expf(x2 - m) + expf(x3 - m));
    if (lane == 0) { stats[r * 2] = m; stats[r * 2 + 1] = e; }
  }

  // (d) cls KL term (wave 7; wave-local)
  if (wave == 7) {
    const float* tcsrc = use ? (queue_all + qoff * Dv) : (t_cls_out + (size_t)bt * Dv);
    float4 t4 = *(const float4*)(tcsrc + lane * 4);
    float* otc = out_tc + (size_t)bt * Dv + lane * 4;  // 4B-aligned only
    otc[0] = t4.x; otc[1] = t4.y; otc[2] = t4.z; otc[3] = t4.w;
    float4 c4 = *(const float4*)(center + lane * 4);
    float x0 = (t4.x - c4.x) * INV_TAU, x1 = (t4.y - c4.y) * INV_TAU;
    float x2 = (t4.z - c4.z) * INV_TAU, x3 = (t4.w - c4.w) * INV_TAU;
    float M = wave_max(fmaxf(fmaxf(x0, x1), fmaxf(x2, x3)));
    float e0 = expf(x0 - M), e1 = expf(x1 - M), e2 = expf(x2 - M), e3 = expf(x3 - M);
    float S = wave_sum(e0 + e1 + e2 + e3);
    float4 s4 = *(const float4*)(s_cls_out + (size_t)bs * Dv + lane * 4);
    float z0 = s4.x * INV_TAU, z1 = s4.y * INV_TAU;
    float z2 = s4.z * INV_TAU, z3 = s4.w * INV_TAU;
    float M2 = wave_max(fmaxf(fmaxf(z0, z1), fmaxf(z2, z3)));
    float S2 = wave_sum(expf(z0 - M2) + expf(z1 - M2) + expf(z2 - M2) + expf(z3 - M2));
    float lse = M2 + logf(S2);
    float cv = 0.5f * wave_sum(e0 * (lse - z0) + e1 * (lse - z1) +
                               e2 * (lse - z2) + e3 * (lse - z3)) / S;
    if (lane == 0) cls_s = cv;
  }
  __syncthreads();

  // ---- teacher row inverse norms (from staged bf16; masked rows are zero) --
  for (int r = wave; r < NP; r += 8) {
    const int ch = (lane >> 1) ^ (r & 7);
    const unsigned short* p = &tfb[r * Dv + ch * 8 + (lane & 1) * 4];
    float a0 = bf2f(p[0]), a1 = bf2f(p[1]), a2 = bf2f(p[2]), a3 = bf2f(p[3]);
    float ss = wave_sum(a0 * a0 + a1 * a1 + a2 * a2 + a3 * a3);
    if (lane == 0) rinv[r] = 1.0f / fmaxf(sqrtf(ss), 1e-12f);
  }
  __syncthreads();

  // ---- MFMA sim, 8-wave split: wave = (half m-block) x (A row-block) ----
  // wave w: A rows (w&3)*16.., m-half (w>>2) -> mb in {half*2, half*2+1}.
  {
    const int half = wave >> 2, wr = wave & 3;
    f32x4 acc[2];
    acc[0] = (f32x4){0.f, 0.f, 0.f, 0.f};
    acc[1] = (f32x4){0.f, 0.f, 0.f, 0.f};
    const int rsel = lane & 15, g = lane >> 4, rsw = lane & 7;
    const int rowA = (wr << 4) + rsel;
#pragma unroll
    for (int kk = 0; kk < 8; kk++) {
      const int ch = (kk * 4 + g) ^ rsw;  // rowA&7 == rowB&7 == lane&7
      bf16x8 a = *(const bf16x8*)&sfb[rowA * Dv + (ch << 3)];
#pragma unroll
      for (int mh = 0; mh < 2; mh++) {
        const int mb = half * 2 + mh;
        bf16x8 b = *(const bf16x8*)&tfb[((mb << 4) + rsel) * Dv + (ch << 3)];
        acc[mh] = __builtin_amdgcn_mfma_f32_16x16x32_bf16(a, b, acc[mh], 0, 0, 0);
      }
    }
    float bv[4] = {-INFINITY, -INFINITY, -INFINITY, -INFINITY};
    int bm[4] = {999, 999, 999, 999};
#pragma unroll
    for (int mh = 0; mh < 2; mh++) {
      const int m = ((half * 2 + mh) << 4) + rsel;
      if (m < NR) {
        const float rv = rinv[m];
#pragma unroll
        for (int r = 0; r < 4; r++) {
          float s = acc[mh][r] * rv;
          if (s > bv[r]) { bv[r] = s; bm[r] = m; }  // m ascending -> first max
        }
      }
    }
#pragma unroll
    for (int o = 1; o < 16; o <<= 1) {
#pragma unroll
      for (int r = 0; r < 4; r++) {
        float ov = __shfl_xor(bv[r], o);
        int om = __shfl_xor(bm[r], o);
        if (ov > bv[r] || (ov == bv[r] && om < bm[r])) { bv[r] = ov; bm[r] = om; }
      }
    }
    if (rsel == 0) {
#pragma unroll
      for (int r = 0; r < 4; r++) {
        const int n = (wr << 4) + (g << 2) + r;
        cand_v[half][n] = bv[r];
        cand_m[half][n] = bm[r];
      }
    }
  }
  __syncthreads();

  // ---- loss rows: y/lse in regs; inline half-combine (tie -> half 0) ------
  float4 tv[7];
  int msj[7];
#pragma unroll
  for (int j = 0; j < 7; j++) {
    const int n = wave + 8 * j;
    if (n < NR) {
      const int ms = (cand_v[1][n] > cand_v[0][n]) ? cand_m[1][n] : cand_m[0][n];
      msj[j] = ms;
      const float* trow = use ? (qg + (size_t)ms * Dv)
                              : (t_region_out + ((size_t)bt * NR + ms) * Dv);
      tv[j] = *(const float4*)(trow + lane * 4);  // L2-hot
    }
  }
  float gacc = 0.f;
#pragma unroll
  for (int j = 0; j < 7; j++) {
    const int n = wave + 8 * j;
    if (n < NR) {
      const int ms = msj[j];
      const float4 v4 = tv[j];
      const float4 y4 = yv[j];
      const float lse = lsev[j];
      float x0 = (v4.x - cg4.x) * INV_TAU, x1 = (v4.y - cg4.y) * INV_TAU;
      float x2 = (v4.z - cg4.z) * INV_TAU, x3 = (v4.w - cg4.w) * INV_TAU;
      float tmax = stats[ms * 2], tsum = stats[ms * 2 + 1];
      float part = wave_sum(expf(x0 - tmax) * (lse - y4.x) +
                            expf(x1 - tmax) * (lse - y4.y) +
                            expf(x2 - tmax) * (lse - y4.z) +
                            expf(x3 - tmax) * (lse - y4.w));
      gacc += part / tsum;
    }
  }
  if (lane == 0) red[wave] = gacc;
  __syncthreads();
  if (tid == 0) {
    float s = red[0] + red[1] + red[2] + red[3] +
              red[4] + red[5] + red[6] + red[7];
    block_part[bt] = cls_s + (0.5f / 49.0f) * s;
  }
}

// ---------------------------------------------------------------------------
// k4: deterministic final reduction. out[0] = sum(block_part)/512
// ---------------------------------------------------------------------------
__global__ __launch_bounds__(256) void k4_final(const float* __restrict__ block_part,
                                                float* __restrict__ out) {
  __shared__ float red[4];
  const int tid = threadIdx.x, lane = tid & 63, wave = tid >> 6;
  float a = block_part[tid] + block_part[tid + 256];
  a = wave_sum(a);
  if (lane == 0) red[wave] = a;
  __syncthreads();
  if (tid == 0)
    out[0] = (red[0] + red[1] + red[2] + red[3]) * (1.0f / 512.0f);
}

extern "C" void kernel_launch(void* const* d_in, const int* in_sizes, int n_in,
                              void* d_out, int out_size, void* d_ws, size_t ws_size,
                              hipStream_t stream) {
  (void)in_sizes; (void)n_in; (void)out_size; (void)ws_size;
  const float* s_cls_out      = (const float*)d_in[0];
  const float* s_region_out   = (const float*)d_in[1];
  const float* s_fea          = (const float*)d_in[2];
  const float* t_cls_out      = (const float*)d_in[3];
  const float* t_region_out   = (const float*)d_in[4];
  const float* t_fea          = (const float*)d_in[5];
  const float* queue_all      = (const float*)d_in[6];
  const float* queue_grid_all = (const float*)d_in[7];
  const float* center         = (const float*)d_in[8];
  const float* center_grid    = (const float*)d_in[9];
  const int* concept_idx      = (const int*)d_in[10];
  const int* pos_idx          = (const int*)d_in[11];
  const unsigned char* use_q  = (const unsigned char*)d_in[12];

  float* out    = (float*)d_out;
  float* out_tc = out + 1;                 // 512*256
  float* out_tr = out + 1 + B2v * Dv;      // 25088*256

  float* block_part = (float*)d_ws;        // 512 floats

  kmain<<<B2v, 512, 0, stream>>>(s_cls_out, s_region_out, s_fea, t_cls_out,
                                 t_region_out, t_fea, queue_all, queue_grid_all,
                                 center, center_grid, concept_idx, pos_idx,
                                 use_q, out_tc, out_tr, block_part);
  k4_final<<<1, 256, 0, stream>>>(block_part, out);
}